// Round 1
// baseline (180.586 us; speedup 1.0000x reference)
//
#include <hip/hip_runtime.h>

// Lorenz96 RK4 step, fp32.
//   dxdt[i] = (x[i+1] - x[i-2]) * x[i-1] - x[i] + 8
//   classic RK4 with step dt (t unused, autonomous).
// One thread per batch row (40 states held in registers, all stage loops
// fully unrolled so the %40 indices are compile-time constants).

#define N_STATE 40
#define FORCE 8.0f

__global__ __launch_bounds__(256)
void lorenz96_rk4_kernel(const float* __restrict__ x0,
                         const float* __restrict__ dt_p,
                         float* __restrict__ out,
                         int batch)
{
    int row = blockIdx.x * blockDim.x + threadIdx.x;
    if (row >= batch) return;

    const float dt = dt_p[0];          // wave-uniform -> s_load, L2-cached
    const float hdt = 0.5f * dt;

    const float* xp = x0 + (size_t)row * N_STATE;
    float*       op = out + (size_t)row * N_STATE;

    float x[N_STATE];
    // 10x float4 vector loads; row stride 160B keeps 16B alignment.
    #pragma unroll
    for (int j = 0; j < N_STATE / 4; ++j) {
        float4 v = ((const float4*)xp)[j];
        x[4 * j + 0] = v.x;
        x[4 * j + 1] = v.y;
        x[4 * j + 2] = v.z;
        x[4 * j + 3] = v.w;
    }

    float acc[N_STATE];   // k1 + 2k2 + 2k3 + k4 accumulator
    float a[N_STATE];     // stage state buffers (ping-pong)
    float b[N_STATE];

    // k1 = f(x);  a = x + 0.5*dt*k1
    #pragma unroll
    for (int i = 0; i < N_STATE; ++i) {
        float k = (x[(i + 1) % N_STATE] - x[(i + 38) % N_STATE])
                  * x[(i + 39) % N_STATE] - x[i] + FORCE;
        acc[i] = k;
        a[i] = x[i] + hdt * k;
    }
    // k2 = f(a);  b = x + 0.5*dt*k2
    #pragma unroll
    for (int i = 0; i < N_STATE; ++i) {
        float k = (a[(i + 1) % N_STATE] - a[(i + 38) % N_STATE])
                  * a[(i + 39) % N_STATE] - a[i] + FORCE;
        acc[i] += 2.0f * k;
        b[i] = x[i] + hdt * k;
    }
    // k3 = f(b);  a = x + dt*k3
    #pragma unroll
    for (int i = 0; i < N_STATE; ++i) {
        float k = (b[(i + 1) % N_STATE] - b[(i + 38) % N_STATE])
                  * b[(i + 39) % N_STATE] - b[i] + FORCE;
        acc[i] += 2.0f * k;
        a[i] = x[i] + dt * k;
    }
    // k4 = f(a)
    #pragma unroll
    for (int i = 0; i < N_STATE; ++i) {
        float k = (a[(i + 1) % N_STATE] - a[(i + 38) % N_STATE])
                  * a[(i + 39) % N_STATE] - a[i] + FORCE;
        acc[i] += k;
    }

    const float s = dt * (1.0f / 6.0f);
    #pragma unroll
    for (int j = 0; j < N_STATE / 4; ++j) {
        float4 v;
        v.x = x[4 * j + 0] + s * acc[4 * j + 0];
        v.y = x[4 * j + 1] + s * acc[4 * j + 1];
        v.z = x[4 * j + 2] + s * acc[4 * j + 2];
        v.w = x[4 * j + 3] + s * acc[4 * j + 3];
        ((float4*)op)[j] = v;
    }
}

extern "C" void kernel_launch(void* const* d_in, const int* in_sizes, int n_in,
                              void* d_out, int out_size, void* d_ws, size_t ws_size,
                              hipStream_t stream) {
    const float* x0 = (const float*)d_in[0];
    // d_in[1] = t (unused, autonomous system)
    const float* dt = (const float*)d_in[2];
    float* out = (float*)d_out;

    int batch = in_sizes[0] / N_STATE;   // 524288
    int block = 256;
    int grid = (batch + block - 1) / block;
    lorenz96_rk4_kernel<<<grid, block, 0, stream>>>(x0, dt, out, batch);
}

// Round 2
// 147.293 us; speedup vs baseline: 1.2260x; 1.2260x over previous
//
#include <hip/hip_runtime.h>

// Lorenz96 RK4, fp32 — coalesced layout:
//   10 lanes per row x 4 elements (1 float4) per lane; 6 rows per wave
//   (lanes 0..59 active, 60..63 idle). Lane l of wave w accesses float4
//   index 60*w + l -> every VMEM instruction is a dense 960B burst and
//   coverage across waves is gapless.
//   Stencil halo (x[i-2], x[i-1], x[i+1]) via 3 __shfl per RK4 stage
//   within the 10-lane row group. No LDS, no __syncthreads.

#define FORCE 8.0f

__global__ __launch_bounds__(256)
void lorenz96_rk4_shfl(const float4* __restrict__ x0,
                       const float* __restrict__ dt_p,
                       float4* __restrict__ out,
                       long nf4)   // batch * 10 float4s total
{
    const long tid  = (long)blockIdx.x * blockDim.x + threadIdx.x;
    const long wave = tid >> 6;
    const int  lane = (int)(tid & 63);
    const int  lrow = lane / 10;          // row within wave, 0..5 (6 = idle)
    const int  c    = lane - lrow * 10;   // float4 column within row, 0..9
    const long f    = wave * 60 + lane;   // global float4 index
    const bool active = (lane < 60) && (f < nf4);

    // neighbor lanes within this row's 10-lane group (circular)
    const int lL = lrow * 10 + (c == 0 ? 9 : c - 1);
    const int lR = lrow * 10 + (c == 9 ? 0 : c + 1);

    const float dt  = dt_p[0];
    const float hdt = 0.5f * dt;

    float4 v = make_float4(0.f, 0.f, 0.f, 0.f);
    if (active) v = x0[f];
    const float x0r = v.x, x1r = v.y, x2r = v.z, x3r = v.w;

    // dxdt for this lane's 4 elements of the current stage state s0..s3.
    // element i: d[i] = (s[i+1] - s[i-2]) * s[i-1] - s[i] + F
    //   i=0 needs left.e2 (i-2), left.e3 (i-1);  i=3 needs right.e0 (i+1)
    auto deriv = [&](float s0, float s1, float s2, float s3,
                     float& d0, float& d1, float& d2, float& d3) {
        float hL2 = __shfl(s2, lL);
        float hL3 = __shfl(s3, lL);
        float hR0 = __shfl(s0, lR);
        d0 = (s1  - hL2) * hL3 - s0 + FORCE;
        d1 = (s2  - hL3) * s0  - s1 + FORCE;
        d2 = (s3  - s0 ) * s1  - s2 + FORCE;
        d3 = (hR0 - s1 ) * s2  - s3 + FORCE;
    };

    float k0, k1, k2, k3;          // stage derivative
    float a0, a1, a2, a3;          // acc = k1 + 2k2 + 2k3 + k4
    float y0, y1, y2, y3;          // stage state

    // k1
    deriv(x0r, x1r, x2r, x3r, k0, k1, k2, k3);
    a0 = k0; a1 = k1; a2 = k2; a3 = k3;
    y0 = x0r + hdt * k0; y1 = x1r + hdt * k1;
    y2 = x2r + hdt * k2; y3 = x3r + hdt * k3;

    // k2
    deriv(y0, y1, y2, y3, k0, k1, k2, k3);
    a0 += 2.0f * k0; a1 += 2.0f * k1; a2 += 2.0f * k2; a3 += 2.0f * k3;
    y0 = x0r + hdt * k0; y1 = x1r + hdt * k1;
    y2 = x2r + hdt * k2; y3 = x3r + hdt * k3;

    // k3
    deriv(y0, y1, y2, y3, k0, k1, k2, k3);
    a0 += 2.0f * k0; a1 += 2.0f * k1; a2 += 2.0f * k2; a3 += 2.0f * k3;
    y0 = x0r + dt * k0; y1 = x1r + dt * k1;
    y2 = x2r + dt * k2; y3 = x3r + dt * k3;

    // k4
    deriv(y0, y1, y2, y3, k0, k1, k2, k3);
    a0 += k0; a1 += k1; a2 += k2; a3 += k3;

    const float s = dt * (1.0f / 6.0f);
    float4 r;
    r.x = x0r + s * a0;
    r.y = x1r + s * a1;
    r.z = x2r + s * a2;
    r.w = x3r + s * a3;
    if (active) out[f] = r;
}

extern "C" void kernel_launch(void* const* d_in, const int* in_sizes, int n_in,
                              void* d_out, int out_size, void* d_ws, size_t ws_size,
                              hipStream_t stream) {
    const float4* x0 = (const float4*)d_in[0];
    // d_in[1] = t (unused; autonomous system)
    const float* dt = (const float*)d_in[2];
    float4* out = (float4*)d_out;

    const long nf4 = (long)in_sizes[0] / 4;        // batch*10 float4s
    const long nwaves = (nf4 + 59) / 60;           // 6 rows (60 f4) per wave
    const int block = 256;                          // 4 waves/block
    const long grid = (nwaves + 3) / 4;
    lorenz96_rk4_shfl<<<dim3((unsigned)grid), dim3(block), 0, stream>>>(x0, dt, out, nf4);
}